// Round 1
// 126.387 us; speedup vs baseline: 1.0071x; 1.0071x over previous
//
#include <hip/hip_runtime.h>
#include <cstdint>
#include <cstddef>

#define BB 8
#define NN 48
#define DD 33
#define XS 40            // xw/sw/ct row stride in floats (16B-aligned, zero-padded)
#define KP 128           // merged-K: [0,40)=xi*xj, [40,80)=xi*s, [80,120)=xj*s, 120=const
#define HH 32
#define MM (NN*NN)       // 2304 rows (i,j)
#define NC (NN*HH)       // 1536 cols (k,h)
#define TILE 96
#define TM (MM/TILE)     // 24 M-tiles
#define TN (NC/TILE)     // 16 N-tiles
#define SPLITM 4         // grid.y
#define MQ (TM/SPLITM)   // 6 M-tiles per block
#define NBLK (TN*SPLITM*BB) // 512 total gemm blocks (ticket target)
#define LDK 136          // LDS row stride f16 (+8 pad)

typedef __attribute__((ext_vector_type(8))) _Float16 f16x8;
typedef __attribute__((ext_vector_type(4))) float f32x4;

// ---- Kernel A: gather xw (padded), s = mean_i x, transpose coefs -> ct,
// ----           zero global h-accumulator + ticket counter -----------------------
__global__ void k_setup(const int* __restrict__ xcat, const float* __restrict__ xfeat,
                        const float* __restrict__ embed, const float* __restrict__ coefs,
                        float* __restrict__ xw, float* __restrict__ sw,
                        float* __restrict__ ct, float* __restrict__ hacc_g,
                        unsigned int* __restrict__ counter) {
    int b = blockIdx.x, t = threadIdx.x;
    if (b < BB) {
        for (int idx = t; idx < NN * XS; idx += 256) {
            int i = idx / XS, d = idx - i * XS;
            float v = 0.f;
            if (d < 32)       v = embed[xcat[b * NN + i] * 32 + d];
            else if (d == 32) v = xfeat[b * NN + i];
            xw[b * NN * XS + idx] = v;
        }
        __syncthreads();
        if (t < XS) {
            float a = 0.f;
            for (int i = 0; i < NN; ++i) a += xw[b * NN * XS + i * XS + t];
            sw[b * XS + t] = a * (1.0f / 48.0f);
        }
    } else if (b == BB) {
        // ct[(q*32+h)*40 + d] = coefs[(d*8+q)*32 + h], zero-padded d>=33
        for (int idx = t; idx < 8 * HH * XS; idx += 256) {
            int qh = idx / XS, d = idx - qh * XS;
            int q = qh >> 5, h = qh & 31;
            ct[idx] = (d < DD) ? coefs[(d * 8 + q) * HH + h] : 0.f;
        }
    } else {
        // re-poison safe: zero accumulators every launch/replay
        if (t < BB * HH) hacc_g[t] = 0.f;
        if (t == 0) *counter = 0u;
    }
}

// ---- Kernel B: fused build(A,B) + 96x96xK MFMA GEMM over 6 M-tiles per block;
// ----           relu + h-sum in regs -> global atomics -> last-block finalize ----
__global__ __launch_bounds__(256, 2) void k_gemm(
        const float* __restrict__ xw, const float* __restrict__ sw,
        const float* __restrict__ ct, const float* __restrict__ eq_bias,
        float* __restrict__ hacc_g, unsigned int* __restrict__ counter,
        const float* __restrict__ out_w, const float* __restrict__ out_b,
        float* __restrict__ out) {
    __shared__ __align__(16) _Float16 As[TILE][LDK];
    __shared__ __align__(16) _Float16 Bs[TILE][LDK];
    __shared__ float gbuf[TILE];
    __shared__ float hacc[HH];
    __shared__ int lastFlag;

    int t = threadIdx.x;
    int bx = blockIdx.x, my = blockIdx.y, b = blockIdx.z;
    int N0 = bx * TILE;
    const float* xb = xw + b * NN * XS;
    const float* sb = sw + b * XS;

    if (t < HH) hacc[t] = 0.f;
    // const-K column values g[n] = sum_d s^2 (c4*x_k + c7*s) + bias_h, n = (k,h)
    if (t < TILE) {
        int n = N0 + t, k = n >> 5, h = n & 31;
        const float* xk = xb + k * XS;
        const float* c4 = ct + (4 * HH + h) * XS;
        const float* c7 = ct + (7 * HH + h) * XS;
        float g = 0.f;
        for (int d = 0; d < DD; ++d) {
            float sd = sb[d];
            g += sd * sd * (c4[d] * xk[d] + c7[d] * sd);
        }
        gbuf[t] = g + eq_bias[h];
    }
    __syncthreads();

    // ---- build B tile (rows = (k,h) of this N-tile), once per block ----
    for (int c = 0; c < 6; ++c) {
        int ch = c * 256 + t;
        int row = ch >> 4, d0 = (ch & 15) * 8;
        int n = N0 + row, k = n >> 5, h = n & 31;
        const float* xk = xb + k * XS;
        f16x8 v;
        if (d0 < 120) {
            int seg = (d0 >= 80) ? 2 : (d0 >= 40) ? 1 : 0;
            int d = d0 - seg * 40;
            const int QA[3] = {0, 2, 1}, QB[3] = {3, 6, 5};
            const float* ca = ct + (QA[seg] * HH + h) * XS + d;
            const float* cb = ct + (QB[seg] * HH + h) * XS + d;
            f32x4 ca0 = *(const f32x4*)(ca),     ca1 = *(const f32x4*)(ca + 4);
            f32x4 cb0 = *(const f32x4*)(cb),     cb1 = *(const f32x4*)(cb + 4);
            f32x4 xk0 = *(const f32x4*)(xk + d), xk1 = *(const f32x4*)(xk + d + 4);
            f32x4 sb0 = *(const f32x4*)(sb + d), sb1 = *(const f32x4*)(sb + d + 4);
            f32x4 r0 = ca0 * xk0 + cb0 * sb0;
            f32x4 r1 = ca1 * xk1 + cb1 * sb1;
            for (int e = 0; e < 4; ++e) { v[e] = (_Float16)r0[e]; v[4 + e] = (_Float16)r1[e]; }
        } else {
            v = (f16x8){0, 0, 0, 0, 0, 0, 0, 0};
            v[0] = (_Float16)gbuf[row];
        }
        *(f16x8*)&Bs[row][d0] = v;
    }

    // ---- A tile builder (rows = (i,j)) ----
    auto buildA = [&](int mt) {
        int M0 = (my * MQ + mt) * TILE;
        for (int c = 0; c < 6; ++c) {
            int ch = c * 256 + t;
            int row = ch >> 4, d0 = (ch & 15) * 8;
            int grow = M0 + row;
            int i = grow / NN, j = grow - i * NN;
            f16x8 v;
            if (d0 < 120) {
                int seg = (d0 >= 80) ? 2 : (d0 >= 40) ? 1 : 0;
                int d = d0 - seg * 40;
                const float* p1 = (seg == 2) ? (xb + j * XS) : (xb + i * XS);
                const float* p2 = (seg == 0) ? (xb + j * XS) : sb;
                f32x4 a0 = *(const f32x4*)(p1 + d), a1 = *(const f32x4*)(p1 + d + 4);
                f32x4 b0 = *(const f32x4*)(p2 + d), b1 = *(const f32x4*)(p2 + d + 4);
                f32x4 r0 = a0 * b0, r1 = a1 * b1;
                for (int e = 0; e < 4; ++e) { v[e] = (_Float16)r0[e]; v[4 + e] = (_Float16)r1[e]; }
            } else {
                v = (f16x8){0, 0, 0, 0, 0, 0, 0, 0};
                v[0] = (_Float16)1.f;
            }
            *(f16x8*)&As[row][d0] = v;
        }
    };

    buildA(0);
    __syncthreads();

    int lane = t & 63, wave = t >> 6;
    int wm = (wave >> 1) * 48, wn = (wave & 1) * 48;
    int lrow = lane & 15, quad = lane >> 4;

    // hoist B fragments for all 4 k-steps (Bs never rewritten)
    f16x8 bf[3][4];
#pragma unroll
    for (int nt = 0; nt < 3; ++nt)
#pragma unroll
        for (int ks = 0; ks < 4; ++ks)
            bf[nt][ks] = *(const f16x8*)&Bs[wn + nt * 16 + lrow][ks * 32 + quad * 8];

    float fs[3] = {0.f, 0.f, 0.f};
    for (int mt = 0; mt < MQ; ++mt) {
        f32x4 acc[3][3];
#pragma unroll
        for (int m3 = 0; m3 < 3; ++m3)
#pragma unroll
            for (int nt = 0; nt < 3; ++nt)
                acc[m3][nt] = (f32x4){0.f, 0.f, 0.f, 0.f};

#pragma unroll
        for (int ks = 0; ks < 4; ++ks) {
            f16x8 af[3];
#pragma unroll
            for (int m3 = 0; m3 < 3; ++m3)
                af[m3] = *(const f16x8*)&As[wm + m3 * 16 + lrow][ks * 32 + quad * 8];
#pragma unroll
            for (int m3 = 0; m3 < 3; ++m3)
#pragma unroll
                for (int nt = 0; nt < 3; ++nt)
                    acc[m3][nt] = __builtin_amdgcn_mfma_f32_16x16x32_f16(af[m3], bf[nt][ks], acc[m3][nt], 0, 0, 0);
        }

#pragma unroll
        for (int m3 = 0; m3 < 3; ++m3)
#pragma unroll
            for (int nt = 0; nt < 3; ++nt)
#pragma unroll
                for (int r = 0; r < 4; ++r)
                    fs[nt] += fmaxf(acc[m3][nt][r], 0.f);

        __syncthreads();                    // all waves done reading As
        if (mt + 1 < MQ) {
            buildA(mt + 1);
            __syncthreads();                // new As ready
        }
    }

    // ---- reduce: quads -> LDS -> global atomics ----
#pragma unroll
    for (int nt = 0; nt < 3; ++nt) {
        float v = fs[nt];
        v += __shfl_xor(v, 16);
        v += __shfl_xor(v, 32);
        if (lane < 16) atomicAdd(&hacc[(wn + nt * 16 + lane) & 31], v);
    }
    __syncthreads();
    if (t < HH) atomicAdd(&hacc_g[b * HH + t], hacc[t]);
    __threadfence();
    __syncthreads();
    if (t == 0) {
        unsigned int tk = atomicAdd(counter, 1u);
        lastFlag = (tk == NBLK - 1) ? 1 : 0;
    }
    __syncthreads();

    // ---- last block finalizes all 8 batches: relu(mean) @ out_w + out_b ----
    if (lastFlag) {
        int bb = t >> 5, h2 = t & 31;
        float v = atomicAdd(&hacc_g[bb * HH + h2], 0.f);   // coherent read via RMW
        float m = v * (1.0f / 110592.0f);
        float r = fmaxf(m, 0.f) * out_w[h2];
        r += __shfl_xor(r, 1);
        r += __shfl_xor(r, 2);
        r += __shfl_xor(r, 4);
        r += __shfl_xor(r, 8);
        r += __shfl_xor(r, 16);
        if (h2 == 0) out[bb] = r + out_b[0];
    }
}

extern "C" void kernel_launch(void* const* d_in, const int* in_sizes, int n_in,
                              void* d_out, int out_size, void* d_ws, size_t ws_size,
                              hipStream_t stream) {
    (void)in_sizes; (void)n_in; (void)out_size; (void)ws_size;
    const int*   xcat    = (const int*)d_in[0];
    const float* xfeat   = (const float*)d_in[1];
    const float* embed   = (const float*)d_in[2];
    const float* coefs   = (const float*)d_in[3];
    const float* eq_bias = (const float*)d_in[4];
    const float* out_w   = (const float*)d_in[5];
    const float* out_b   = (const float*)d_in[6];
    float* out = (float*)d_out;

    // Workspace layout (16B-aligned), total ~105 KB
    char* w = (char*)d_ws;
    float*        xw      = (float*)(w + 0);        // 8*48*40 f32 = 61440 B
    float*        sw      = (float*)(w + 61440);    // 8*40 f32    = 1280 B
    float*        ct      = (float*)(w + 62720);    // 8*32*40 f32 = 40960 B
    float*        hacc_g  = (float*)(w + 103680);   // 8*32 f32    = 1024 B
    unsigned int* counter = (unsigned int*)(w + 104704); // 4 B

    k_setup<<<dim3(BB + 2), dim3(256), 0, stream>>>(xcat, xfeat, embed, coefs,
                                                    xw, sw, ct, hacc_g, counter);
    k_gemm<<<dim3(TN, SPLITM, BB), dim3(256), 0, stream>>>(xw, sw, ct, eq_bias,
                                                           hacc_g, counter,
                                                           out_w, out_b, out);
}